// Round 7
// baseline (1183.785 us; speedup 1.0000x reference)
//
#include <hip/hip_runtime.h>
#include <hip/hip_bf16.h>
#include <math.h>

#define NN 30000
#define MM 16
#define F 128
#define NMROWS (NN*MM)
constexpr float BN_EPS = 1e-5f;

using bf16x8 = __attribute__((ext_vector_type(8))) short;
using f32x4v = __attribute__((ext_vector_type(4))) float;
using f32x16v = __attribute__((ext_vector_type(16))) float;

// ---- workspace float offsets ----
#define WS_NODE   0u
#define WS_S      3840000u
#define WS_T      7680000u       // holds w2p/w3p after last pass2
#define WS_SUM    11520000u
#define WS_LOGIT  15360000u      // holds convPack + wUp until k_u is done
#define WS_RED    15840000u
#define WS_STATS  15841024u
// within stats region:
#define ST_BN1SUM 0u
#define ST_BN1SQ  384u
#define ST_BN2SUM 768u
#define ST_BN2SQ  1152u
#define ST_W1E    2048u
#define ST_W1D    2688u
#define ST_B1EFF  2816u
#define ST_END    2944u

__device__ __forceinline__ float read_tp(const int* tp) {
  int ti = tp[0];
  return (ti >= -1000 && ti <= 1000) ? (float)ti : __int_as_float(ti);
}

// exact 3-chunk bf16 split (truncation; x = c0 + c1 + c2 + O(2^-24 x))
__device__ __forceinline__ void split3(float x, short& a, short& b, short& c) {
  unsigned u0 = __float_as_uint(x);
  a = (short)(u0 >> 16);
  float r1 = x - __uint_as_float(u0 & 0xFFFF0000u);
  unsigned u1 = __float_as_uint(r1);
  b = (short)(u1 >> 16);
  float r2 = r1 - __uint_as_float(u1 & 0xFFFF0000u);
  c = (short)(__float_as_uint(r2) >> 16);
}

// Pack conv W' (3 layers, 16x16 frag layout for k_gemm) and pi_W1 into split-3 bf16.
// W'[k][col] = col<128 ? Wl[k][col] : Wl[128+k][col-128]
__global__ void k_pack_conv(const float* __restrict__ cW, const float* __restrict__ pW1,
                            short* __restrict__ convPack, short* __restrict__ wUp) {
  int tid = threadIdx.x, l = blockIdx.x;
  if (l < 3) {
    const float* Wl = cW + (size_t)l*261*256;
    short* dst = convPack + (size_t)l*98304;
    for (int it = 0; it < 8; ++it) {
      int slot = it*512 + tid;
      int ln = slot & 63, f = slot >> 6;
      int nt = f & 15, ks = f >> 4;
      int colg = nt*16 + (ln & 15);
      int kb = ks*32 + (ln >> 4)*8;
      bf16x8 h, m, lo;
      #pragma unroll
      for (int i = 0; i < 8; ++i) {
        int k = kb + i;
        float v = (colg < 128) ? Wl[(size_t)k*256 + colg]
                               : Wl[(size_t)(128 + k)*256 + (colg - 128)];
        short a, b, c; split3(v, a, b, c);
        h[i] = a; m[i] = b; lo[i] = c;
      }
      *(bf16x8*)&dst[((size_t)((0*4 + ks)*16 + nt))*512 + ln*8] = h;
      *(bf16x8*)&dst[((size_t)((1*4 + ks)*16 + nt))*512 + ln*8] = m;
      *(bf16x8*)&dst[((size_t)((2*4 + ks)*16 + nt))*512 + ln*8] = lo;
    }
  } else {
    for (int it = 0; it < 4; ++it) {
      int slot = it*512 + tid;
      int ln = slot & 63, f = slot >> 6;
      int nt = f & 7, ks = f >> 3;
      int colg = nt*16 + (ln & 15);
      int kb = ks*32 + (ln >> 4)*8;
      bf16x8 h, m, lo;
      #pragma unroll
      for (int i = 0; i < 8; ++i) {
        float v = pW1[(size_t)(kb + i)*128 + colg];
        short a, b, c; split3(v, a, b, c);
        h[i] = a; m[i] = b; lo[i] = c;
      }
      *(bf16x8*)&wUp[((size_t)((0*4 + ks)*8 + nt))*512 + ln*8] = h;
      *(bf16x8*)&wUp[((size_t)((1*4 + ks)*8 + nt))*512 + ln*8] = m;
      *(bf16x8*)&wUp[((size_t)((2*4 + ks)*8 + nt))*512 + ln*8] = lo;
    }
  }
}

// Unified fused GEMM (16x16x32 frags): A-row production + split-3 MFMA. 32 rows/block.
__global__ __launch_bounds__(512, 6) void k_gemm(
    const float* __restrict__ nf, const float* __restrict__ embW, const float* __restrict__ embB,
    float* __restrict__ node, const float* __restrict__ summed,
    const float* __restrict__ bsum2, const float* __restrict__ bsq2,
    const float* __restrict__ g2, const float* __restrict__ b2,
    const short* __restrict__ Wp, const float* __restrict__ bias,
    float* __restrict__ outS, float* __restrict__ outT,
    int NT, int mode, int writeNode) {
  __shared__ __align__(16) short sb[32*392];
  __shared__ float nfL[32][20];
  __shared__ float ewL[19][128];
  int tid = threadIdx.x;
  int n0 = blockIdx.x*32;
  if (mode == 0) {
    for (int i = tid; i < 32*19; i += 512) {
      int r = i/19, k = i - r*19;
      int n = n0 + r;
      nfL[r][k] = (n < NN) ? nf[(size_t)n*19 + k] : 0.f;
    }
    for (int i = tid; i < 19*128; i += 512) ewL[i >> 7][i & 127] = embW[i];
  }
  __syncthreads();
  {
    int c = tid & 127, rg = tid >> 7;
    float scv = 0.f, shv = 0.f, eb = 0.f;
    if (mode == 0) {
      eb = embB[c];
    } else {
      const float inv_n = 1.f / (float)NN;
      float mu = bsum2[c]*inv_n;
      float var = bsq2[c]*inv_n - mu*mu;
      scv = g2[c]*rsqrtf(var + BN_EPS);
      shv = b2[c] - mu*scv;
    }
    #pragma unroll
    for (int rr = 0; rr < 8; ++rr) {
      int r = rg*8 + rr;
      int n = n0 + r;
      float v = 0.f;
      if (n < NN) {
        if (mode == 0) {
          v = eb;
          #pragma unroll
          for (int k = 0; k < 19; ++k) v = fmaf(nfL[r][k], ewL[k][c], v);
        } else {
          float x = node[(size_t)n*F + c] + fmaf(summed[(size_t)n*F + c], scv, shv);
          v = fmaxf(x, 0.f) + log1pf(expf(-fabsf(x)));
        }
        if (writeNode) node[(size_t)n*F + c] = v;
      }
      short s0, s1, s2; split3(v, s0, s1, s2);
      sb[r*392 + c] = s0; sb[r*392 + 128 + c] = s1; sb[r*392 + 256 + c] = s2;
    }
  }
  __syncthreads();
  int wv = tid >> 6, ln = tid & 63, lr = ln & 15, lg2 = ln >> 4;
  int ntpw = NT >> 3;            // 2 (conv) or 1 (k_u)
  f32x4v z4 = {0.f,0.f,0.f,0.f};
  f32x4v acc0[2] = {z4,z4};
  f32x4v acc1[2] = {z4,z4};
  int nt0 = wv*ntpw, nt1 = wv*ntpw + 1;
  for (int ks = 0; ks < 4; ++ks) {
    #pragma unroll
    for (int bs = 0; bs < 3; ++bs) {
      bf16x8 B0 = *(const bf16x8*)&Wp[((size_t)((bs*4 + ks)*NT + nt0))*512 + ln*8];
      bf16x8 B1 = B0;
      if (ntpw == 2) B1 = *(const bf16x8*)&Wp[((size_t)((bs*4 + ks)*NT + nt1))*512 + ln*8];
      int na = 3 - bs;
      #pragma unroll
      for (int as = 0; as < 3; ++as) {
        if (as >= na) break;
        #pragma unroll
        for (int mt = 0; mt < 2; ++mt) {
          bf16x8 a = *(const bf16x8*)&sb[(mt*16 + lr)*392 + as*128 + ks*32 + lg2*8];
          acc0[mt] = __builtin_amdgcn_mfma_f32_16x16x32_bf16(a, B0, acc0[mt], 0, 0, 0);
          if (ntpw == 2)
            acc1[mt] = __builtin_amdgcn_mfma_f32_16x16x32_bf16(a, B1, acc1[mt], 0, 0, 0);
        }
      }
    }
  }
  {
    int col = nt0*16 + lr;
    float bb = (col < 128) ? bias[col] : 0.f;
    #pragma unroll
    for (int mt = 0; mt < 2; ++mt) {
      #pragma unroll
      for (int rr = 0; rr < 4; ++rr) {
        int row = n0 + mt*16 + lg2*4 + rr;
        if (row < NN) {
          float x = acc0[mt][rr] + bb;
          if (col < 128) outS[(size_t)row*F + col] = x;
          else outT[(size_t)row*F + col - 128] = x;
        }
      }
    }
  }
  if (ntpw == 2) {
    int col = nt1*16 + lr;
    float bb = (col < 128) ? bias[col] : 0.f;
    #pragma unroll
    for (int mt = 0; mt < 2; ++mt) {
      #pragma unroll
      for (int rr = 0; rr < 4; ++rr) {
        int row = n0 + mt*16 + lg2*4 + rr;
        if (row < NN) {
          float x = acc1[mt][rr] + bb;
          if (col < 128) outS[(size_t)row*F + col] = x;
          else outT[(size_t)row*F + col - 128] = x;
        }
      }
    }
  }
}

// pass 1: bn1 stats over all 480000 rows. Scalar channel-per-thread gather.
__global__ __launch_bounds__(256, 8) void k_stats(
    const float* __restrict__ S, const float* __restrict__ T,
    const float* __restrict__ Wl, const float* __restrict__ edge,
    const int* __restrict__ idx,
    float* __restrict__ bsum, float* __restrict__ bsq) {
  __shared__ float eL[1280];
  __shared__ int gL[256];
  __shared__ float rA[256], rB[256];
  int tid = threadIdx.x;
  int n0 = blockIdx.x*16;
  for (int i = tid; i < 1280; i += 256) eL[i] = edge[(size_t)n0*80 + i];
  {
    int v = idx[n0*MM + tid];
    gL[tid] = v < 0 ? v + NN : v;
  }
  __syncthreads();
  int c = tid & 127, h = tid >> 7;
  float we[5];
  #pragma unroll
  for (int j = 0; j < 5; ++j) we[j] = Wl[(size_t)(256+j)*256 + c];
  float s1 = 0.f, s2 = 0.f;
  for (int nl = h*8; nl < h*8 + 8; ++nl) {
    float sv = S[(size_t)(n0+nl)*F + c];
    #pragma unroll
    for (int m = 0; m < MM; ++m) {
      int row = nl*MM + m;
      float g = sv + T[(size_t)gL[row]*F + c];
      const float* e = &eL[row*5];
      #pragma unroll
      for (int j = 0; j < 5; ++j) g = fmaf(e[j], we[j], g);
      s1 += g; s2 = fmaf(g, g, s2);
    }
  }
  rA[tid] = s1; rB[tid] = s2;
  __syncthreads();
  if (h == 0) {
    atomicAdd(&bsum[c], s1 + rA[128 + c]);
    atomicAdd(&bsq[c],  s2 + rB[128 + c]);
  }
}

// pass 2: inline bn1 finalize; summed + bn2 stats. Scalar channel-per-thread gather.
__global__ __launch_bounds__(256, 6) void k_pass2(
    const float* __restrict__ S, const float* __restrict__ T,
    const float* __restrict__ Wl, const float* __restrict__ edge,
    const int* __restrict__ idx,
    const float* __restrict__ bsum1, const float* __restrict__ bsq1,
    const float* __restrict__ g1, const float* __restrict__ b1,
    float* __restrict__ summed, float* __restrict__ bsum2, float* __restrict__ bsq2) {
  __shared__ float eL[1280];
  __shared__ int gL[256];
  __shared__ float mk[256];
  __shared__ float rA[256], rB[256];
  int tid = threadIdx.x;
  int n0 = blockIdx.x*16;
  for (int i = tid; i < 1280; i += 256) eL[i] = edge[(size_t)n0*80 + i];
  {
    int v = idx[n0*MM + tid];
    mk[tid] = v >= 0 ? 1.f : 0.f;
    gL[tid] = v < 0 ? v + NN : v;
  }
  __syncthreads();
  int c = tid & 127, h = tid >> 7;
  float we[5];
  #pragma unroll
  for (int j = 0; j < 5; ++j) we[j] = Wl[(size_t)(256+j)*256 + c];
  float sc1v, sh1v;
  {
    const float inv_n = 1.f / (float)NMROWS;
    float mu = bsum1[c]*inv_n;
    float var = bsq1[c]*inv_n - mu*mu;
    sc1v = g1[c]*rsqrtf(var + BN_EPS);
    sh1v = b1[c] - mu*sc1v;
  }
  float st1 = 0.f, st2 = 0.f;
  for (int nl = h*8; nl < h*8 + 8; ++nl) {
    float sv = S[(size_t)(n0+nl)*F + c];
    float acc = 0.f;
    #pragma unroll
    for (int m = 0; m < MM; ++m) {
      int row = nl*MM + m;
      float g = sv + T[(size_t)gL[row]*F + c];
      const float* e = &eL[row*5];
      #pragma unroll
      for (int j = 0; j < 5; ++j) g = fmaf(e[j], we[j], g);
      float x = fmaf(g, sc1v, sh1v);
      float sig = 1.f/(1.f + expf(-x));
      acc = fmaf(mk[row]*sig, sig, acc);
    }
    summed[(size_t)(n0+nl)*F + c] = acc;
    st1 += acc; st2 = fmaf(acc, acc, st2);
  }
  rA[tid] = st1; rB[tid] = st2;
  __syncthreads();
  if (h == 0) {
    atomicAdd(&bsum2[c], st1 + rA[128 + c]);
    atomicAdd(&bsq2[c],  st2 + rB[128 + c]);
  }
}

// fold tiled-edge / repeated-distance / constant-tp columns of pi_W1
__global__ void k_pi_const(const float* __restrict__ W1, const float* __restrict__ b1,
                           const int* __restrict__ tp,
                           float* __restrict__ w1e, float* __restrict__ w1d, float* __restrict__ b1eff) {
  int c = threadIdx.x;
  float t = read_tp(tp);
  #pragma unroll
  for (int j = 0; j < 5; ++j) w1e[j*128 + c] = W1[(128+j)*128 + c] + W1[(133+j)*128 + c];
  float d = 0.f;
  #pragma unroll
  for (int r = 138; r < 143; ++r) d += W1[r*128 + c];
  w1d[c] = d;
  float tt = 0.f;
  #pragma unroll
  for (int r = 143; r < 148; ++r) tt += W1[r*128 + c];
  b1eff[c] = b1[c] + t*tt;
}

// pack W2 (128x256) and W3 (256x128) into split-3 bf16 32x32x16 B-fragment layout.
// lane l: col = nt*32 + (l&31), k = ks*16 + (l>>5)*8 + i
// w2p: ((bs*8 + ks)*8 + nt)*512 + l*8   (8 nt of 32 cols, 8 ks of K16)
// w3p: ((bs*16 + ks)*4 + nt)*512 + l*8  (4 nt of 32 cols, 16 ks of K16)
__global__ void k_packw(const float* __restrict__ W2, const float* __restrict__ W3,
                        short* __restrict__ w2p, short* __restrict__ w3p) {
  int tid = threadIdx.x;
  if (blockIdx.x == 0) {
    for (int it = 0; it < 8; ++it) {
      int slot = it*512 + tid;
      int ln = slot & 63, fr = slot >> 6;   // fr 0..63
      int nt = fr & 7, ks = fr >> 3;
      int col = nt*32 + (ln & 31);
      int kb = ks*16 + (ln >> 5)*8;
      bf16x8 h, m, l;
      #pragma unroll
      for (int i = 0; i < 8; ++i) {
        short a, b, c;
        split3(W2[(size_t)(kb + i)*256 + col], a, b, c);
        h[i] = a; m[i] = b; l[i] = c;
      }
      *(bf16x8*)&w2p[((size_t)((0*8 + ks)*8 + nt))*512 + ln*8] = h;
      *(bf16x8*)&w2p[((size_t)((1*8 + ks)*8 + nt))*512 + ln*8] = m;
      *(bf16x8*)&w2p[((size_t)((2*8 + ks)*8 + nt))*512 + ln*8] = l;
    }
  } else {
    for (int it = 0; it < 8; ++it) {
      int slot = it*512 + tid;
      int ln = slot & 63, fr = slot >> 6;   // fr 0..63
      int nt = fr & 3, ks = fr >> 2;
      int col = nt*32 + (ln & 31);
      int kb = ks*16 + (ln >> 5)*8;
      bf16x8 h, m, l;
      #pragma unroll
      for (int i = 0; i < 8; ++i) {
        short a, b, c;
        split3(W3[(size_t)(kb + i)*128 + col], a, b, c);
        h[i] = a; m[i] = b; l[i] = c;
      }
      *(bf16x8*)&w3p[((size_t)((0*16 + ks)*4 + nt))*512 + ln*8] = h;
      *(bf16x8*)&w3p[((size_t)((1*16 + ks)*4 + nt))*512 + ln*8] = m;
      *(bf16x8*)&w3p[((size_t)((2*16 + ks)*4 + nt))*512 + ln*8] = l;
    }
  }
}

// fused pi MLP via split-bf16 32x32x16 MFMA, 2 independent acc chains per stage.
// 32 rows/block, 512 threads (8 waves).
__global__ __launch_bounds__(512, 6) void k_pi_mfma(
    const float* __restrict__ U, const float* __restrict__ b2,
    const float* __restrict__ b3, const float* __restrict__ W4, const float* __restrict__ b4,
    const short* __restrict__ w2p, const short* __restrict__ w3p,
    const float* __restrict__ edge, const int* __restrict__ idx, const float* __restrict__ dist,
    const int* __restrict__ tp,
    const float* __restrict__ w1e, const float* __restrict__ w1d,
    float* __restrict__ lgt) {
  __shared__ __align__(16) short buf[32*776];     // h1 (stride 392) aliased under h2 (stride 776)
  __shared__ float eeL[32][5];
  __shared__ float ddL[32];
  __shared__ int gxL[32], ivL[32];
  __shared__ float part[4][32];
  int tid = threadIdx.x;
  int rb = blockIdx.x*32;
  for (int i = tid; i < 160; i += 512) eeL[i/5][i%5] = edge[(size_t)rb*5 + i];
  if (tid < 32) {
    int v = idx[rb + tid];
    ivL[tid] = v;
    gxL[tid] = v < 0 ? v + NN : v;
    ddL[tid] = dist[rb + tid];
  }
  __syncthreads();

  // ---- stage A: h1 = relu(U[gather] + e@W1e + d*w1d), split3 -> LDS (row stride 392) ----
  {
    int c = tid & 127, rg = tid >> 7;
    float wd = w1d[c];
    float wE[5];
    #pragma unroll
    for (int j = 0; j < 5; ++j) wE[j] = w1e[j*128 + c];
    #pragma unroll
    for (int rr = 0; rr < 8; ++rr) {
      int r = rg*8 + rr;
      float v = U[(size_t)gxL[r]*F + c];
      v = fmaf(ddL[r], wd, v);
      #pragma unroll
      for (int j = 0; j < 5; ++j) v = fmaf(eeL[r][j], wE[j], v);
      v = fmaxf(v, 0.f);
      short s0, s1, s2; split3(v, s0, s1, s2);
      buf[r*392 + c] = s0; buf[r*392 + 128 + c] = s1; buf[r*392 + 256 + c] = s2;
    }
  }
  __syncthreads();

  int wv = tid >> 6, ln = tid & 63;
  int lc = ln & 31, l5 = ln >> 5;
  f32x16v zz16 = {0.f,0.f,0.f,0.f,0.f,0.f,0.f,0.f,0.f,0.f,0.f,0.f,0.f,0.f,0.f,0.f};

  // ---- stage B: h2 = relu(h1 @ W2 + b2); wave -> n-tile wv (32 cols); 2 acc chains ----
  f32x16v accB0 = zz16, accB1 = zz16;
  #pragma unroll 2
  for (int ks = 0; ks < 8; ++ks) {
    bf16x8 Bh = *(const bf16x8*)&w2p[((size_t)((0*8 + ks)*8 + wv))*512 + ln*8];
    bf16x8 Bm = *(const bf16x8*)&w2p[((size_t)((1*8 + ks)*8 + wv))*512 + ln*8];
    bf16x8 Bl = *(const bf16x8*)&w2p[((size_t)((2*8 + ks)*8 + wv))*512 + ln*8];
    bf16x8 a0 = *(const bf16x8*)&buf[lc*392 + 0*128 + ks*16 + l5*8];
    bf16x8 a1 = *(const bf16x8*)&buf[lc*392 + 1*128 + ks*16 + l5*8];
    bf16x8 a2 = *(const bf16x8*)&buf[lc*392 + 2*128 + ks*16 + l5*8];
    accB0 = __builtin_amdgcn_mfma_f32_32x32x16_bf16(a0, Bh, accB0, 0, 0, 0);
    accB1 = __builtin_amdgcn_mfma_f32_32x32x16_bf16(a1, Bh, accB1, 0, 0, 0);
    accB0 = __builtin_amdgcn_mfma_f32_32x32x16_bf16(a2, Bh, accB0, 0, 0, 0);
    accB1 = __builtin_amdgcn_mfma_f32_32x32x16_bf16(a0, Bm, accB1, 0, 0, 0);
    accB0 = __builtin_amdgcn_mfma_f32_32x32x16_bf16(a1, Bm, accB0, 0, 0, 0);
    accB1 = __builtin_amdgcn_mfma_f32_32x32x16_bf16(a0, Bl, accB1, 0, 0, 0);
  }
  f32x16v accB = accB0 + accB1;
  __syncthreads();   // all waves done reading h1
  // write h2 splits; C/D: col=lane&31, row=(reg&3)+8*(reg>>2)+4*(lane>>5)
  {
    int col = wv*32 + lc;
    float bb = b2[col];
    #pragma unroll
    for (int reg = 0; reg < 16; ++reg) {
      int row = (reg & 3) + 8*(reg >> 2) + 4*l5;
      float x = fmaxf(accB[reg] + bb, 0.f);
      short s0, s1, s2; split3(x, s0, s1, s2);
      buf[row*776 + col] = s0; buf[row*776 + 256 + col] = s1; buf[row*776 + 512 + col] = s2;
    }
  }
  __syncthreads();

  // ---- stage C: h3 = relu(h2 @ W3 + b3); wave pair: nt = wv>>1, K-half = wv&1; 2 acc chains ----
  f32x16v accC0 = zz16, accC1 = zz16;
  int ntc = wv >> 1, kh = wv & 1;
  #pragma unroll 2
  for (int ks = 0; ks < 8; ++ks) {
    int kstep = kh*8 + ks;
    bf16x8 Bh = *(const bf16x8*)&w3p[((size_t)((0*16 + kstep)*4 + ntc))*512 + ln*8];
    bf16x8 Bm = *(const bf16x8*)&w3p[((size_t)((1*16 + kstep)*4 + ntc))*512 + ln*8];
    bf16x8 Bl = *(const bf16x8*)&w3p[((size_t)((2*16 + kstep)*4 + ntc))*512 + ln*8];
    bf16x8 a0 = *(const bf16x8*)&buf[lc*776 + 0*256 + kstep*16 + l5*8];
    bf16x8 a1 = *(const bf16x8*)&buf[lc*776 + 1*256 + kstep*16 + l5*8];
    bf16x8 a2 = *(const bf16x8*)&buf[lc*776 + 2*256 + kstep*16 + l5*8];
    accC0 = __builtin_amdgcn_mfma_f32_32x32x16_bf16(a0, Bh, accC0, 0, 0, 0);
    accC1 = __builtin_amdgcn_mfma_f32_32x32x16_bf16(a1, Bh, accC1, 0, 0, 0);
    accC0 = __builtin_amdgcn_mfma_f32_32x32x16_bf16(a2, Bh, accC0, 0, 0, 0);
    accC1 = __builtin_amdgcn_mfma_f32_32x32x16_bf16(a0, Bm, accC1, 0, 0, 0);
    accC0 = __builtin_amdgcn_mfma_f32_32x32x16_bf16(a1, Bm, accC0, 0, 0, 0);
    accC1 = __builtin_amdgcn_mfma_f32_32x32x16_bf16(a0, Bl, accC1, 0, 0, 0);
  }
  f32x16v accC = accC0 + accC1;
  __syncthreads();   // all waves done reading h2 -> buf reusable as scratch
  float* scr = (float*)buf;           // [4][64] lanes x 17-stride x 16 regs (conflict-free)
  if (kh == 1) {
    int base = (ntc*64 + ln)*17;
    #pragma unroll
    for (int reg = 0; reg < 16; ++reg) scr[base + reg] = accC[reg];
  }
  __syncthreads();

  // ---- stage D: combine K-halves; logit = relu(h3)@W4 (+b4) ----
  if (kh == 0) {
    int base = (ntc*64 + ln)*17;
    float w4c = W4[ntc*32 + lc];
    float b3c = b3[ntc*32 + lc];
    float p[16];
    #pragma unroll
    for (int reg = 0; reg < 16; ++reg) {
      float v = accC[reg] + scr[base + reg];
      p[reg] = fmaxf(v + b3c, 0.f) * w4c;
    }
    #pragma unroll
    for (int off = 1; off < 32; off <<= 1) {
      #pragma unroll
      for (int reg = 0; reg < 16; ++reg) p[reg] += __shfl_xor(p[reg], off);
    }
    if (lc == 0) {
      #pragma unroll
      for (int reg = 0; reg < 16; ++reg) {
        int row = (reg & 3) + 8*(reg >> 2) + 4*l5;
        part[ntc][row] = p[reg];
      }
    }
  }
  __syncthreads();
  if (tid < 32) {
    float s = part[0][tid] + part[1][tid] + part[2][tid] + part[3][tid];
    float tpf = read_tp(tp);
    float lgv = s + b4[0];
    float am = (ivL[tid] >= 0 && eeL[tid][4] <= tpf) ? 0.f : 1.f;
    lgt[rb + tid] = lgv - 1e8f*am;
  }
}

// per-block max + sum(exp(x - bmax))
__global__ void k_pass1(const float* __restrict__ lg, float* __restrict__ red) {
  __shared__ float r[256];
  int t = threadIdx.x;
  float m = -3.4e38f;
  for (int i = blockIdx.x*256 + t; i < NMROWS; i += 512*256) m = fmaxf(m, lg[i]);
  r[t] = m; __syncthreads();
  for (int s = 128; s > 0; s >>= 1) {
    if (t < s) r[t] = fmaxf(r[t], r[t + s]);
    __syncthreads();
  }
  float bm = r[0];
  __syncthreads();
  float sum = 0.f;
  for (int i = blockIdx.x*256 + t; i < NMROWS; i += 512*256) sum += expf(lg[i] - bm);
  r[t] = sum; __syncthreads();
  for (int s = 128; s > 0; s >>= 1) {
    if (t < s) r[t] += r[t + s];
    __syncthreads();
  }
  if (t == 0) { red[blockIdx.x] = bm; red[512 + blockIdx.x] = r[0]; }
}

// final: redundant reduce per block, then write softmax
__global__ void k_out2(const float* __restrict__ lg, const float* __restrict__ red,
                       float* __restrict__ out) {
  __shared__ float r[256], z[256];
  int t = threadIdx.x;
  float m = fmaxf(red[t], red[t + 256]);
  r[t] = m; __syncthreads();
  for (int s = 128; s > 0; s >>= 1) {
    if (t < s) r[t] = fmaxf(r[t], r[t + s]);
    __syncthreads();
  }
  float gmax = r[0];
  __syncthreads();
  float zz = red[512 + t]*expf(red[t] - gmax) + red[768 + t]*expf(red[256 + t] - gmax);
  z[t] = zz; __syncthreads();
  for (int s = 128; s > 0; s >>= 1) {
    if (t < s) z[t] += z[t + s];
    __syncthreads();
  }
  float invZ = 1.f / z[0];
  int i = blockIdx.x*256 + t;
  if (i < NMROWS) out[i] = expf(lg[i] - gmax)*invZ;
}

extern "C" void kernel_launch(void* const* d_in, const int* in_sizes, int n_in,
                              void* d_out, int out_size, void* d_ws, size_t ws_size,
                              hipStream_t stream) {
  (void)in_sizes; (void)n_in; (void)out_size;
  const float* node_fea = (const float*)d_in[0];
  const float* edge_fea = (const float*)d_in[1];
  const int*   eidx     = (const int*)d_in[2];
  const float* dist     = (const float*)d_in[3];
  const int*   tp       = (const int*)d_in[4];
  const float* emb_W    = (const float*)d_in[5];
  const float* emb_b    = (const float*)d_in[6];
  const float* cW       = (const float*)d_in[7];
  const float* cb       = (const float*)d_in[8];
  const float* bn1g     = (const float*)d_in[9];
  const float* bn1b     = (const float*)d_in[10];
  const float* bn2g     = (const float*)d_in[11];
  const float* bn2b     = (const float*)d_in[12];
  const float* pW1      = (const float*)d_in[13];
  const float* pb1      = (const float*)d_in[14];
  const float* pW2      = (const float*)d_in[15];
  const float* pb2      = (const float*)d_in[16];
  const float* pW3      = (const float*)d_in[17];
  const float* pb3      = (const float*)d_in[18];
  const float* pW4      = (const float*)d_in[19];
  const float* pb4      = (const float*)d_in[20];
  float* out = (float*)d_out;
  float* ws  = (float*)d_ws;

  if (ws_size < (size_t)(WS_STATS + ST_END)*sizeof(float)) return;

  float* stats = ws + WS_STATS;
  float* node   = ws + WS_NODE;
  float* Sbuf   = ws + WS_S;
  float* Tbuf   = ws + WS_T;
  float* sumbuf = ws + WS_SUM;
  hipMemsetAsync(stats, 0, 1536*sizeof(float), stream);

  // packs living in the (not-yet-used) logits region
  short* convPack = (short*)(ws + WS_LOGIT);            // 294912 shorts
  short* wUp      = (short*)(ws + WS_LOGIT + 300000u);  // 49152 shorts
  k_pack_conv<<<4, 512, 0, stream>>>(cW, pW1, convPack, wUp);
  k_pi_const<<<1, 128, 0, stream>>>(pW1, pb1, tp, stats + ST_W1E, stats + ST_W1D, stats + ST_B1EFF);

  for (int l = 0; l < 3; ++l) {
    const float* Wl = cW + (size_t)l*261*256;
    if (l == 0) {
      k_gemm<<<938, 512, 0, stream>>>(node_fea, emb_W, emb_b, node,
                                      nullptr, nullptr, nullptr, nullptr, nullptr,
                                      convPack, cb, Sbuf, Tbuf, 16, 0, 1);
    } else {
      k_gemm<<<938, 512, 0, stream>>>(nullptr, nullptr, nullptr, node,
                                      sumbuf, stats + ST_BN2SUM + (l-1)*128, stats + ST_BN2SQ + (l-1)*128,
                                      bn2g + (l-1)*128, bn2b + (l-1)*128,
                                      convPack + (size_t)l*98304, cb + l*256, Sbuf, Tbuf, 16, 1, 1);
    }
    k_stats<<<1875, 256, 0, stream>>>(Sbuf, Tbuf, Wl, edge_fea, eidx,
                                      stats + ST_BN1SUM + l*128, stats + ST_BN1SQ + l*128);
    k_pass2<<<1875, 256, 0, stream>>>(Sbuf, Tbuf, Wl, edge_fea, eidx,
                                      stats + ST_BN1SUM + l*128, stats + ST_BN1SQ + l*128,
                                      bn1g + l*256, bn1b + l*256,
                                      sumbuf, stats + ST_BN2SUM + l*128, stats + ST_BN2SQ + l*128);
  }

  // pi packs into the (now dead) T region
  short* w2p = (short*)(ws + WS_T);             // 98304 shorts
  short* w3p = (short*)(ws + WS_T + 49152u);    // 98304 shorts
  k_packw<<<2, 512, 0, stream>>>(pW2, pW3, w2p, w3p);

  // U = softplus(node + bn2_l2(summed)) @ pi_W1[:128] + b1eff   (fused update, no node write)
  k_gemm<<<938, 512, 0, stream>>>(nullptr, nullptr, nullptr, node,
                                  sumbuf, stats + ST_BN2SUM + 2*128, stats + ST_BN2SQ + 2*128,
                                  bn2g + 2*128, bn2b + 2*128,
                                  wUp, stats + ST_B1EFF, Sbuf, Sbuf, 8, 1, 0);

  k_pi_mfma<<<15000, 512, 0, stream>>>(Sbuf, pb2, pb3, pW4, pb4, w2p, w3p,
                                       edge_fea, eidx, dist, tp,
                                       stats + ST_W1E, stats + ST_W1D, ws + WS_LOGIT);

  k_pass1<<<512, 256, 0, stream>>>(ws + WS_LOGIT, ws + WS_RED);
  k_out2<<<1875, 256, 0, stream>>>(ws + WS_LOGIT, ws + WS_RED, out);
}

// Round 9
// 1103.002 us; speedup vs baseline: 1.0732x; 1.0732x over previous
//
#include <hip/hip_runtime.h>
#include <hip/hip_bf16.h>
#include <math.h>

#define NN 30000
#define MM 16
#define F 128
#define NMROWS (NN*MM)
constexpr float BN_EPS = 1e-5f;

using bf16x8 = __attribute__((ext_vector_type(8))) short;
using f32x4v = __attribute__((ext_vector_type(4))) float;

// ---- workspace float offsets ----
#define WS_NODE   0u
#define WS_S      3840000u
#define WS_T      7680000u       // holds w2p/w3p after last pass2
#define WS_SUM    11520000u
#define WS_LOGIT  15360000u      // holds convPack + wUp until k_u is done
#define WS_RED    15840000u
#define WS_STATS  15841024u
// within stats region:
#define ST_BN1SUM 0u
#define ST_BN1SQ  384u
#define ST_BN2SUM 768u
#define ST_BN2SQ  1152u
#define ST_W1E    2048u
#define ST_W1D    2688u
#define ST_B1EFF  2816u
#define ST_END    2944u

__device__ __forceinline__ float read_tp(const int* tp) {
  int ti = tp[0];
  return (ti >= -1000 && ti <= 1000) ? (float)ti : __int_as_float(ti);
}

// exact 3-chunk bf16 split (truncation; x = c0 + c1 + c2 + O(2^-24 x))
__device__ __forceinline__ void split3(float x, short& a, short& b, short& c) {
  unsigned u0 = __float_as_uint(x);
  a = (short)(u0 >> 16);
  float r1 = x - __uint_as_float(u0 & 0xFFFF0000u);
  unsigned u1 = __float_as_uint(r1);
  b = (short)(u1 >> 16);
  float r2 = r1 - __uint_as_float(u1 & 0xFFFF0000u);
  c = (short)(__float_as_uint(r2) >> 16);
}

// Pack conv W' (3 layers, 16x16 frag layout for k_gemm) and pi_W1 into split-3 bf16.
// W'[k][col] = col<128 ? Wl[k][col] : Wl[128+k][col-128]
__global__ void k_pack_conv(const float* __restrict__ cW, const float* __restrict__ pW1,
                            short* __restrict__ convPack, short* __restrict__ wUp) {
  int tid = threadIdx.x, l = blockIdx.x;
  if (l < 3) {
    const float* Wl = cW + (size_t)l*261*256;
    short* dst = convPack + (size_t)l*98304;
    for (int it = 0; it < 8; ++it) {
      int slot = it*512 + tid;
      int ln = slot & 63, f = slot >> 6;
      int nt = f & 15, ks = f >> 4;
      int colg = nt*16 + (ln & 15);
      int kb = ks*32 + (ln >> 4)*8;
      bf16x8 h, m, lo;
      #pragma unroll
      for (int i = 0; i < 8; ++i) {
        int k = kb + i;
        float v = (colg < 128) ? Wl[(size_t)k*256 + colg]
                               : Wl[(size_t)(128 + k)*256 + (colg - 128)];
        short a, b, c; split3(v, a, b, c);
        h[i] = a; m[i] = b; lo[i] = c;
      }
      *(bf16x8*)&dst[((size_t)((0*4 + ks)*16 + nt))*512 + ln*8] = h;
      *(bf16x8*)&dst[((size_t)((1*4 + ks)*16 + nt))*512 + ln*8] = m;
      *(bf16x8*)&dst[((size_t)((2*4 + ks)*16 + nt))*512 + ln*8] = lo;
    }
  } else {
    for (int it = 0; it < 4; ++it) {
      int slot = it*512 + tid;
      int ln = slot & 63, f = slot >> 6;
      int nt = f & 7, ks = f >> 3;
      int colg = nt*16 + (ln & 15);
      int kb = ks*32 + (ln >> 4)*8;
      bf16x8 h, m, lo;
      #pragma unroll
      for (int i = 0; i < 8; ++i) {
        float v = pW1[(size_t)(kb + i)*128 + colg];
        short a, b, c; split3(v, a, b, c);
        h[i] = a; m[i] = b; lo[i] = c;
      }
      *(bf16x8*)&wUp[((size_t)((0*4 + ks)*8 + nt))*512 + ln*8] = h;
      *(bf16x8*)&wUp[((size_t)((1*4 + ks)*8 + nt))*512 + ln*8] = m;
      *(bf16x8*)&wUp[((size_t)((2*4 + ks)*8 + nt))*512 + ln*8] = lo;
    }
  }
}

// Unified fused GEMM (16x16x32 frags): A-row production + split-3 MFMA. 32 rows/block.
__global__ __launch_bounds__(512, 6) void k_gemm(
    const float* __restrict__ nf, const float* __restrict__ embW, const float* __restrict__ embB,
    float* __restrict__ node, const float* __restrict__ summed,
    const float* __restrict__ bsum2, const float* __restrict__ bsq2,
    const float* __restrict__ g2, const float* __restrict__ b2,
    const short* __restrict__ Wp, const float* __restrict__ bias,
    float* __restrict__ outS, float* __restrict__ outT,
    int NT, int mode, int writeNode) {
  __shared__ __align__(16) short sb[32*392];
  __shared__ float nfL[32][20];
  __shared__ float ewL[19][128];
  int tid = threadIdx.x;
  int n0 = blockIdx.x*32;
  if (mode == 0) {
    for (int i = tid; i < 32*19; i += 512) {
      int r = i/19, k = i - r*19;
      int n = n0 + r;
      nfL[r][k] = (n < NN) ? nf[(size_t)n*19 + k] : 0.f;
    }
    for (int i = tid; i < 19*128; i += 512) ewL[i >> 7][i & 127] = embW[i];
  }
  __syncthreads();
  {
    int c = tid & 127, rg = tid >> 7;
    float scv = 0.f, shv = 0.f, eb = 0.f;
    if (mode == 0) {
      eb = embB[c];
    } else {
      const float inv_n = 1.f / (float)NN;
      float mu = bsum2[c]*inv_n;
      float var = bsq2[c]*inv_n - mu*mu;
      scv = g2[c]*rsqrtf(var + BN_EPS);
      shv = b2[c] - mu*scv;
    }
    #pragma unroll
    for (int rr = 0; rr < 8; ++rr) {
      int r = rg*8 + rr;
      int n = n0 + r;
      float v = 0.f;
      if (n < NN) {
        if (mode == 0) {
          v = eb;
          #pragma unroll
          for (int k = 0; k < 19; ++k) v = fmaf(nfL[r][k], ewL[k][c], v);
        } else {
          float x = node[(size_t)n*F + c] + fmaf(summed[(size_t)n*F + c], scv, shv);
          v = fmaxf(x, 0.f) + log1pf(expf(-fabsf(x)));
        }
        if (writeNode) node[(size_t)n*F + c] = v;
      }
      short s0, s1, s2; split3(v, s0, s1, s2);
      sb[r*392 + c] = s0; sb[r*392 + 128 + c] = s1; sb[r*392 + 256 + c] = s2;
    }
  }
  __syncthreads();
  int wv = tid >> 6, ln = tid & 63, lr = ln & 15, lg2 = ln >> 4;
  int ntpw = NT >> 3;            // 2 (conv) or 1 (k_u)
  f32x4v z4 = {0.f,0.f,0.f,0.f};
  f32x4v acc0[2] = {z4,z4};
  f32x4v acc1[2] = {z4,z4};
  int nt0 = wv*ntpw, nt1 = wv*ntpw + 1;
  for (int ks = 0; ks < 4; ++ks) {
    #pragma unroll
    for (int bs = 0; bs < 3; ++bs) {
      bf16x8 B0 = *(const bf16x8*)&Wp[((size_t)((bs*4 + ks)*NT + nt0))*512 + ln*8];
      bf16x8 B1 = B0;
      if (ntpw == 2) B1 = *(const bf16x8*)&Wp[((size_t)((bs*4 + ks)*NT + nt1))*512 + ln*8];
      int na = 3 - bs;
      #pragma unroll
      for (int as = 0; as < 3; ++as) {
        if (as >= na) break;
        #pragma unroll
        for (int mt = 0; mt < 2; ++mt) {
          bf16x8 a = *(const bf16x8*)&sb[(mt*16 + lr)*392 + as*128 + ks*32 + lg2*8];
          acc0[mt] = __builtin_amdgcn_mfma_f32_16x16x32_bf16(a, B0, acc0[mt], 0, 0, 0);
          if (ntpw == 2)
            acc1[mt] = __builtin_amdgcn_mfma_f32_16x16x32_bf16(a, B1, acc1[mt], 0, 0, 0);
        }
      }
    }
  }
  {
    int col = nt0*16 + lr;
    float bb = (col < 128) ? bias[col] : 0.f;
    #pragma unroll
    for (int mt = 0; mt < 2; ++mt) {
      #pragma unroll
      for (int rr = 0; rr < 4; ++rr) {
        int row = n0 + mt*16 + lg2*4 + rr;
        if (row < NN) {
          float x = acc0[mt][rr] + bb;
          if (col < 128) outS[(size_t)row*F + col] = x;
          else outT[(size_t)row*F + col - 128] = x;
        }
      }
    }
  }
  if (ntpw == 2) {
    int col = nt1*16 + lr;
    float bb = (col < 128) ? bias[col] : 0.f;
    #pragma unroll
    for (int mt = 0; mt < 2; ++mt) {
      #pragma unroll
      for (int rr = 0; rr < 4; ++rr) {
        int row = n0 + mt*16 + lg2*4 + rr;
        if (row < NN) {
          float x = acc1[mt][rr] + bb;
          if (col < 128) outS[(size_t)row*F + col] = x;
          else outT[(size_t)row*F + col - 128] = x;
        }
      }
    }
  }
}

// pass 1: bn1 stats over all 480000 rows. Scalar channel-per-thread gather.
__global__ __launch_bounds__(256, 8) void k_stats(
    const float* __restrict__ S, const float* __restrict__ T,
    const float* __restrict__ Wl, const float* __restrict__ edge,
    const int* __restrict__ idx,
    float* __restrict__ bsum, float* __restrict__ bsq) {
  __shared__ float eL[1280];
  __shared__ int gL[256];
  __shared__ float rA[256], rB[256];
  int tid = threadIdx.x;
  int n0 = blockIdx.x*16;
  for (int i = tid; i < 1280; i += 256) eL[i] = edge[(size_t)n0*80 + i];
  {
    int v = idx[n0*MM + tid];
    gL[tid] = v < 0 ? v + NN : v;
  }
  __syncthreads();
  int c = tid & 127, h = tid >> 7;
  float we[5];
  #pragma unroll
  for (int j = 0; j < 5; ++j) we[j] = Wl[(size_t)(256+j)*256 + c];
  float s1 = 0.f, s2 = 0.f;
  for (int nl = h*8; nl < h*8 + 8; ++nl) {
    float sv = S[(size_t)(n0+nl)*F + c];
    #pragma unroll
    for (int m = 0; m < MM; ++m) {
      int row = nl*MM + m;
      float g = sv + T[(size_t)gL[row]*F + c];
      const float* e = &eL[row*5];
      #pragma unroll
      for (int j = 0; j < 5; ++j) g = fmaf(e[j], we[j], g);
      s1 += g; s2 = fmaf(g, g, s2);
    }
  }
  rA[tid] = s1; rB[tid] = s2;
  __syncthreads();
  if (h == 0) {
    atomicAdd(&bsum[c], s1 + rA[128 + c]);
    atomicAdd(&bsq[c],  s2 + rB[128 + c]);
  }
}

// pass 2: inline bn1 finalize; summed + bn2 stats. Scalar channel-per-thread gather.
__global__ __launch_bounds__(256, 6) void k_pass2(
    const float* __restrict__ S, const float* __restrict__ T,
    const float* __restrict__ Wl, const float* __restrict__ edge,
    const int* __restrict__ idx,
    const float* __restrict__ bsum1, const float* __restrict__ bsq1,
    const float* __restrict__ g1, const float* __restrict__ b1,
    float* __restrict__ summed, float* __restrict__ bsum2, float* __restrict__ bsq2) {
  __shared__ float eL[1280];
  __shared__ int gL[256];
  __shared__ float mk[256];
  __shared__ float rA[256], rB[256];
  int tid = threadIdx.x;
  int n0 = blockIdx.x*16;
  for (int i = tid; i < 1280; i += 256) eL[i] = edge[(size_t)n0*80 + i];
  {
    int v = idx[n0*MM + tid];
    mk[tid] = v >= 0 ? 1.f : 0.f;
    gL[tid] = v < 0 ? v + NN : v;
  }
  __syncthreads();
  int c = tid & 127, h = tid >> 7;
  float we[5];
  #pragma unroll
  for (int j = 0; j < 5; ++j) we[j] = Wl[(size_t)(256+j)*256 + c];
  float sc1v, sh1v;
  {
    const float inv_n = 1.f / (float)NMROWS;
    float mu = bsum1[c]*inv_n;
    float var = bsq1[c]*inv_n - mu*mu;
    sc1v = g1[c]*rsqrtf(var + BN_EPS);
    sh1v = b1[c] - mu*sc1v;
  }
  float st1 = 0.f, st2 = 0.f;
  for (int nl = h*8; nl < h*8 + 8; ++nl) {
    float sv = S[(size_t)(n0+nl)*F + c];
    float acc = 0.f;
    #pragma unroll
    for (int m = 0; m < MM; ++m) {
      int row = nl*MM + m;
      float g = sv + T[(size_t)gL[row]*F + c];
      const float* e = &eL[row*5];
      #pragma unroll
      for (int j = 0; j < 5; ++j) g = fmaf(e[j], we[j], g);
      float x = fmaf(g, sc1v, sh1v);
      float sig = 1.f/(1.f + expf(-x));
      acc = fmaf(mk[row]*sig, sig, acc);
    }
    summed[(size_t)(n0+nl)*F + c] = acc;
    st1 += acc; st2 = fmaf(acc, acc, st2);
  }
  rA[tid] = st1; rB[tid] = st2;
  __syncthreads();
  if (h == 0) {
    atomicAdd(&bsum2[c], st1 + rA[128 + c]);
    atomicAdd(&bsq2[c],  st2 + rB[128 + c]);
  }
}

// fold tiled-edge / repeated-distance / constant-tp columns of pi_W1
__global__ void k_pi_const(const float* __restrict__ W1, const float* __restrict__ b1,
                           const int* __restrict__ tp,
                           float* __restrict__ w1e, float* __restrict__ w1d, float* __restrict__ b1eff) {
  int c = threadIdx.x;
  float t = read_tp(tp);
  #pragma unroll
  for (int j = 0; j < 5; ++j) w1e[j*128 + c] = W1[(128+j)*128 + c] + W1[(133+j)*128 + c];
  float d = 0.f;
  #pragma unroll
  for (int r = 138; r < 143; ++r) d += W1[r*128 + c];
  w1d[c] = d;
  float tt = 0.f;
  #pragma unroll
  for (int r = 143; r < 148; ++r) tt += W1[r*128 + c];
  b1eff[c] = b1[c] + t*tt;
}

// pack W2 (128x256) and W3 (256x128) into 3-split bf16 16x16x32 B-fragment layout.
__global__ void k_packw(const float* __restrict__ W2, const float* __restrict__ W3,
                        short* __restrict__ w2p, short* __restrict__ w3p) {
  int tid = threadIdx.x;
  if (blockIdx.x == 0) {
    for (int it = 0; it < 8; ++it) {
      int slot = it*512 + tid;
      int ln = slot & 63, fr = slot >> 6;
      int nt = fr & 15, ks = fr >> 4;
      int col = nt*16 + (ln & 15);
      int kb = ks*32 + (ln >> 4)*8;
      bf16x8 h, m, l;
      #pragma unroll
      for (int i = 0; i < 8; ++i) {
        short a, b, c;
        split3(W2[(size_t)(kb + i)*256 + col], a, b, c);
        h[i] = a; m[i] = b; l[i] = c;
      }
      *(bf16x8*)&w2p[((size_t)((0*4 + ks)*16 + nt))*512 + ln*8] = h;
      *(bf16x8*)&w2p[((size_t)((1*4 + ks)*16 + nt))*512 + ln*8] = m;
      *(bf16x8*)&w2p[((size_t)((2*4 + ks)*16 + nt))*512 + ln*8] = l;
    }
  } else {
    for (int it = 0; it < 8; ++it) {
      int slot = it*512 + tid;
      int ln = slot & 63, fr = slot >> 6;
      int nt = fr & 7, ks = fr >> 3;
      int col = nt*16 + (ln & 15);
      int kb = ks*32 + (ln >> 4)*8;
      bf16x8 h, m, l;
      #pragma unroll
      for (int i = 0; i < 8; ++i) {
        short a, b, c;
        split3(W3[(size_t)(kb + i)*128 + col], a, b, c);
        h[i] = a; m[i] = b; l[i] = c;
      }
      *(bf16x8*)&w3p[((size_t)((0*8 + ks)*8 + nt))*512 + ln*8] = h;
      *(bf16x8*)&w3p[((size_t)((1*8 + ks)*8 + nt))*512 + ln*8] = m;
      *(bf16x8*)&w3p[((size_t)((2*8 + ks)*8 + nt))*512 + ln*8] = l;
    }
  }
}

// fused pi MLP via split-bf16 16x16x32 MFMA. 32 rows/block, 512 threads (8 waves), ~52KB LDS.
__global__ __launch_bounds__(512, 6) void k_pi_mfma(
    const float* __restrict__ U, const float* __restrict__ b2,
    const float* __restrict__ b3, const float* __restrict__ W4, const float* __restrict__ b4,
    const short* __restrict__ w2p, const short* __restrict__ w3p,
    const float* __restrict__ edge, const int* __restrict__ idx, const float* __restrict__ dist,
    const int* __restrict__ tp,
    const float* __restrict__ w1e, const float* __restrict__ w1d,
    float* __restrict__ lgt) {
  __shared__ __align__(16) short buf[32*776];
  __shared__ float eeL[32][5];
  __shared__ float ddL[32];
  __shared__ int gxL[32], ivL[32];
  __shared__ float part[8][32];
  int tid = threadIdx.x;
  int rb = blockIdx.x*32;
  for (int i = tid; i < 160; i += 512) eeL[i/5][i%5] = edge[(size_t)rb*5 + i];
  if (tid < 32) {
    int v = idx[rb + tid];
    ivL[tid] = v;
    gxL[tid] = v < 0 ? v + NN : v;
    ddL[tid] = dist[rb + tid];
  }
  __syncthreads();

  // ---- stage A: h1 = relu(U[gather] + e@W1e + d*w1d), split3 -> LDS ----
  {
    int c = tid & 127, rg = tid >> 7;
    float wd = w1d[c];
    float wE[5];
    #pragma unroll
    for (int j = 0; j < 5; ++j) wE[j] = w1e[j*128 + c];
    #pragma unroll
    for (int rr = 0; rr < 8; ++rr) {
      int r = rg*8 + rr;
      float v = U[(size_t)gxL[r]*F + c];
      v = fmaf(ddL[r], wd, v);
      #pragma unroll
      for (int j = 0; j < 5; ++j) v = fmaf(eeL[r][j], wE[j], v);
      v = fmaxf(v, 0.f);
      short s0, s1, s2; split3(v, s0, s1, s2);
      buf[r*392 + c] = s0; buf[r*392 + 128 + c] = s1; buf[r*392 + 256 + c] = s2;
    }
  }
  __syncthreads();

  int wv = tid >> 6, ln = tid & 63;
  int lr = ln & 15, lg2 = ln >> 4;
  f32x4v zz = {0.f, 0.f, 0.f, 0.f};

  // ---- stage B: h2 = relu(h1 @ W2 + b2) ----
  f32x4v accB[2][2];
  accB[0][0] = zz; accB[0][1] = zz; accB[1][0] = zz; accB[1][1] = zz;
  {
    int nt0 = wv*2, nt1 = wv*2 + 1;
    for (int ks = 0; ks < 4; ++ks) {
      #pragma unroll
      for (int bs = 0; bs < 3; ++bs) {
        bf16x8 B0 = *(const bf16x8*)&w2p[((size_t)((bs*4 + ks)*16 + nt0))*512 + ln*8];
        bf16x8 B1 = *(const bf16x8*)&w2p[((size_t)((bs*4 + ks)*16 + nt1))*512 + ln*8];
        int na = 3 - bs;
        #pragma unroll
        for (int as = 0; as < 3; ++as) {
          if (as >= na) break;
          #pragma unroll
          for (int mt = 0; mt < 2; ++mt) {
            bf16x8 a = *(const bf16x8*)&buf[(mt*16 + lr)*392 + as*128 + ks*32 + lg2*8];
            accB[mt][0] = __builtin_amdgcn_mfma_f32_16x16x32_bf16(a, B0, accB[mt][0], 0, 0, 0);
            accB[mt][1] = __builtin_amdgcn_mfma_f32_16x16x32_bf16(a, B1, accB[mt][1], 0, 0, 0);
          }
        }
      }
    }
  }
  __syncthreads();
  {
    #pragma unroll
    for (int ntl = 0; ntl < 2; ++ntl) {
      int col = (wv*2 + ntl)*16 + lr;
      float bb = b2[col];
      #pragma unroll
      for (int mt = 0; mt < 2; ++mt) {
        #pragma unroll
        for (int r = 0; r < 4; ++r) {
          int row = mt*16 + lg2*4 + r;
          float x = fmaxf(accB[mt][ntl][r] + bb, 0.f);
          short s0, s1, s2; split3(x, s0, s1, s2);
          buf[row*776 + col] = s0; buf[row*776 + 256 + col] = s1; buf[row*776 + 512 + col] = s2;
        }
      }
    }
  }
  __syncthreads();

  // ---- stage C: h3 = relu(h2 @ W3 + b3) ----
  f32x4v accC[2];
  accC[0] = zz; accC[1] = zz;
  {
    for (int ks = 0; ks < 8; ++ks) {
      #pragma unroll
      for (int bs = 0; bs < 3; ++bs) {
        bf16x8 B = *(const bf16x8*)&w3p[((size_t)((bs*8 + ks)*8 + wv))*512 + ln*8];
        int na = 3 - bs;
        #pragma unroll
        for (int as = 0; as < 3; ++as) {
          if (as >= na) break;
          #pragma unroll
          for (int mt = 0; mt < 2; ++mt) {
            bf16x8 a = *(const bf16x8*)&buf[(mt*16 + lr)*776 + as*256 + ks*32 + lg2*8];
            accC[mt] = __builtin_amdgcn_mfma_f32_16x16x32_bf16(a, B, accC[mt], 0, 0, 0);
          }
        }
      }
    }
  }

  // ---- stage D: logit = relu(h3)@W4 (+b4) ----
  {
    float w4c = W4[wv*16 + lr];
    float b3c = b3[wv*16 + lr];
    #pragma unroll
    for (int mt = 0; mt < 2; ++mt) {
      float p0 = fmaxf(accC[mt][0] + b3c, 0.f) * w4c;
      float p1 = fmaxf(accC[mt][1] + b3c, 0.f) * w4c;
      float p2 = fmaxf(accC[mt][2] + b3c, 0.f) * w4c;
      float p3 = fmaxf(accC[mt][3] + b3c, 0.f) * w4c;
      #pragma unroll
      for (int off = 1; off < 16; off <<= 1) {
        p0 += __shfl_xor(p0, off, 16);
        p1 += __shfl_xor(p1, off, 16);
        p2 += __shfl_xor(p2, off, 16);
        p3 += __shfl_xor(p3, off, 16);
      }
      if (lr == 0) {
        int row = mt*16 + lg2*4;
        part[wv][row]   = p0;
        part[wv][row+1] = p1;
        part[wv][row+2] = p2;
        part[wv][row+3] = p3;
      }
    }
  }
  __syncthreads();
  if (tid < 32) {
    float s = 0.f;
    #pragma unroll
    for (int w = 0; w < 8; ++w) s += part[w][tid];
    float tpf = read_tp(tp);
    float lgv = s + b4[0];
    float am = (ivL[tid] >= 0 && eeL[tid][4] <= tpf) ? 0.f : 1.f;
    lgt[rb + tid] = lgv - 1e8f*am;
  }
}

// per-block max + sum(exp(x - bmax))
__global__ void k_pass1(const float* __restrict__ lg, float* __restrict__ red) {
  __shared__ float r[256];
  int t = threadIdx.x;
  float m = -3.4e38f;
  for (int i = blockIdx.x*256 + t; i < NMROWS; i += 512*256) m = fmaxf(m, lg[i]);
  r[t] = m; __syncthreads();
  for (int s = 128; s > 0; s >>= 1) {
    if (t < s) r[t] = fmaxf(r[t], r[t + s]);
    __syncthreads();
  }
  float bm = r[0];
  __syncthreads();
  float sum = 0.f;
  for (int i = blockIdx.x*256 + t; i < NMROWS; i += 512*256) sum += expf(lg[i] - bm);
  r[t] = sum; __syncthreads();
  for (int s = 128; s > 0; s >>= 1) {
    if (t < s) r[t] += r[t + s];
    __syncthreads();
  }
  if (t == 0) { red[blockIdx.x] = bm; red[512 + blockIdx.x] = r[0]; }
}

// final: redundant reduce per block, then write softmax
__global__ void k_out2(const float* __restrict__ lg, const float* __restrict__ red,
                       float* __restrict__ out) {
  __shared__ float r[256], z[256];
  int t = threadIdx.x;
  float m = fmaxf(red[t], red[t + 256]);
  r[t] = m; __syncthreads();
  for (int s = 128; s > 0; s >>= 1) {
    if (t < s) r[t] = fmaxf(r[t], r[t + s]);
    __syncthreads();
  }
  float gmax = r[0];
  __syncthreads();
  float zz = red[512 + t]*expf(red[t] - gmax) + red[768 + t]*expf(red[256 + t] - gmax);
  z[t] = zz; __syncthreads();
  for (int s = 128; s > 0; s >>= 1) {
    if (t < s) z[t] += z[t + s];
    __syncthreads();
  }
  float invZ = 1.f / z[0];
  int i = blockIdx.x*256 + t;
  if (i < NMROWS) out[i] = expf(lg[i] - gmax)*invZ;
}

extern "C" void kernel_launch(void* const* d_in, const int* in_sizes, int n_in,
                              void* d_out, int out_size, void* d_ws, size_t ws_size,
                              hipStream_t stream) {
  (void)in_sizes; (void)n_in; (void)out_size;
  const float* node_fea = (const float*)d_in[0];
  const float* edge_fea = (const float*)d_in[1];
  const int*   eidx     = (const int*)d_in[2];
  const float* dist     = (const float*)d_in[3];
  const int*   tp       = (const int*)d_in[4];
  const float* emb_W    = (const float*)d_in[5];
  const float* emb_b    = (const float*)d_in[6];
  const float* cW       = (const float*)d_in[7];
  const float* cb       = (const float*)d_in[8];
  const float* bn1g     = (const float*)d_in[9];
  const float* bn1b     = (const float*)d_in[10];
  const float* bn2g     = (const float*)d_in[11];
  const float* bn2b     = (const float*)d_in[12];
  const float* pW1      = (const float*)d_in[13];
  const float* pb1      = (const float*)d_in[14];
  const float* pW2      = (const float*)d_in[15];
  const float* pb2      = (const float*)d_in[16];
  const float* pW3      = (const float*)d_in[17];
  const float* pb3      = (const float*)d_in[18];
  const float* pW4      = (const float*)d_in[19];
  const float* pb4      = (const float*)d_in[20];
  float* out = (float*)d_out;
  float* ws  = (float*)d_ws;

  if (ws_size < (size_t)(WS_STATS + ST_END)*sizeof(float)) return;

  float* stats = ws + WS_STATS;
  float* node   = ws + WS_NODE;
  float* Sbuf   = ws + WS_S;
  float* Tbuf   = ws + WS_T;
  float* sumbuf = ws + WS_SUM;
  hipMemsetAsync(stats, 0, 1536*sizeof(float), stream);

  // packs living in the (not-yet-used) logits region
  short* convPack = (short*)(ws + WS_LOGIT);            // 294912 shorts
  short* wUp      = (short*)(ws + WS_LOGIT + 300000u);  // 49152 shorts
  k_pack_conv<<<4, 512, 0, stream>>>(cW, pW1, convPack, wUp);
  k_pi_const<<<1, 128, 0, stream>>>(pW1, pb1, tp, stats + ST_W1E, stats + ST_W1D, stats + ST_B1EFF);

  for (int l = 0; l < 3; ++l) {
    const float* Wl = cW + (size_t)l*261*256;
    if (l == 0) {
      k_gemm<<<938, 512, 0, stream>>>(node_fea, emb_W, emb_b, node,
                                      nullptr, nullptr, nullptr, nullptr, nullptr,
                                      convPack, cb, Sbuf, Tbuf, 16, 0, 1);
    } else {
      k_gemm<<<938, 512, 0, stream>>>(nullptr, nullptr, nullptr, node,
                                      sumbuf, stats + ST_BN2SUM + (l-1)*128, stats + ST_BN2SQ + (l-1)*128,
                                      bn2g + (l-1)*128, bn2b + (l-1)*128,
                                      convPack + (size_t)l*98304, cb + l*256, Sbuf, Tbuf, 16, 1, 1);
    }
    k_stats<<<1875, 256, 0, stream>>>(Sbuf, Tbuf, Wl, edge_fea, eidx,
                                      stats + ST_BN1SUM + l*128, stats + ST_BN1SQ + l*128);
    k_pass2<<<1875, 256, 0, stream>>>(Sbuf, Tbuf, Wl, edge_fea, eidx,
                                      stats + ST_BN1SUM + l*128, stats + ST_BN1SQ + l*128,
                                      bn1g + l*256, bn1b + l*256,
                                      sumbuf, stats + ST_BN2SUM + l*128, stats + ST_BN2SQ + l*128);
  }

  // pi packs into the (now dead) T region
  short* w2p = (short*)(ws + WS_T);             // 98304 shorts
  short* w3p = (short*)(ws + WS_T + 49152u);    // 98304 shorts
  k_packw<<<2, 512, 0, stream>>>(pW2, pW3, w2p, w3p);

  // U = softplus(node + bn2_l2(summed)) @ pi_W1[:128] + b1eff   (fused update, no node write)
  k_gemm<<<938, 512, 0, stream>>>(nullptr, nullptr, nullptr, node,
                                  sumbuf, stats + ST_BN2SUM + 2*128, stats + ST_BN2SQ + 2*128,
                                  bn2g + 2*128, bn2b + 2*128,
                                  wUp, stats + ST_B1EFF, Sbuf, Sbuf, 8, 1, 0);

  k_pi_mfma<<<15000, 512, 0, stream>>>(Sbuf, pb2, pb3, pW4, pb4, w2p, w3p,
                                       edge_fea, eidx, dist, tp,
                                       stats + ST_W1E, stats + ST_W1D, ws + WS_LOGIT);

  k_pass1<<<512, 256, 0, stream>>>(ws + WS_LOGIT, ws + WS_RED);
  k_out2<<<1875, 256, 0, stream>>>(ws + WS_LOGIT, ws + WS_RED, out);
}

// Round 10
// 1085.545 us; speedup vs baseline: 1.0905x; 1.0161x over previous
//
#include <hip/hip_runtime.h>
#include <hip/hip_bf16.h>
#include <math.h>

#define NN 30000
#define MM 16
#define F 128
#define NMROWS (NN*MM)
constexpr float BN_EPS = 1e-5f;

using bf16x8 = __attribute__((ext_vector_type(8))) short;
using f32x4v = __attribute__((ext_vector_type(4))) float;

// ---- workspace float offsets ----
#define WS_NODE   0u
#define WS_S      3840000u
#define WS_T      7680000u       // holds w2p/w3p after last pass2
#define WS_SUM    11520000u
#define WS_LOGIT  15360000u      // holds convPack + wUp until k_u is done
#define WS_RED    15840000u
#define WS_STATS  15841024u
// within stats region:
#define ST_BN1SUM 0u
#define ST_BN1SQ  384u
#define ST_BN2SUM 768u
#define ST_BN2SQ  1152u
#define ST_W1E    2048u
#define ST_W1D    2688u
#define ST_B1EFF  2816u
#define ST_END    2944u

__device__ __forceinline__ float read_tp(const int* tp) {
  int ti = tp[0];
  return (ti >= -1000 && ti <= 1000) ? (float)ti : __int_as_float(ti);
}

// exact 3-chunk bf16 split (truncation; x = c0 + c1 + c2 + O(2^-24 x))
__device__ __forceinline__ void split3(float x, short& a, short& b, short& c) {
  unsigned u0 = __float_as_uint(x);
  a = (short)(u0 >> 16);
  float r1 = x - __uint_as_float(u0 & 0xFFFF0000u);
  unsigned u1 = __float_as_uint(r1);
  b = (short)(u1 >> 16);
  float r2 = r1 - __uint_as_float(u1 & 0xFFFF0000u);
  c = (short)(__float_as_uint(r2) >> 16);
}

// Pack conv W' (3 layers, 16x16 frag layout for k_gemm) and pi_W1 into split-3 bf16.
// W'[k][col] = col<128 ? Wl[k][col] : Wl[128+k][col-128]
__global__ void k_pack_conv(const float* __restrict__ cW, const float* __restrict__ pW1,
                            short* __restrict__ convPack, short* __restrict__ wUp) {
  int tid = threadIdx.x, l = blockIdx.x;
  if (l < 3) {
    const float* Wl = cW + (size_t)l*261*256;
    short* dst = convPack + (size_t)l*98304;
    for (int it = 0; it < 8; ++it) {
      int slot = it*512 + tid;
      int ln = slot & 63, f = slot >> 6;
      int nt = f & 15, ks = f >> 4;
      int colg = nt*16 + (ln & 15);
      int kb = ks*32 + (ln >> 4)*8;
      bf16x8 h, m, lo;
      #pragma unroll
      for (int i = 0; i < 8; ++i) {
        int k = kb + i;
        float v = (colg < 128) ? Wl[(size_t)k*256 + colg]
                               : Wl[(size_t)(128 + k)*256 + (colg - 128)];
        short a, b, c; split3(v, a, b, c);
        h[i] = a; m[i] = b; lo[i] = c;
      }
      *(bf16x8*)&dst[((size_t)((0*4 + ks)*16 + nt))*512 + ln*8] = h;
      *(bf16x8*)&dst[((size_t)((1*4 + ks)*16 + nt))*512 + ln*8] = m;
      *(bf16x8*)&dst[((size_t)((2*4 + ks)*16 + nt))*512 + ln*8] = lo;
    }
  } else {
    for (int it = 0; it < 4; ++it) {
      int slot = it*512 + tid;
      int ln = slot & 63, f = slot >> 6;
      int nt = f & 7, ks = f >> 3;
      int colg = nt*16 + (ln & 15);
      int kb = ks*32 + (ln >> 4)*8;
      bf16x8 h, m, lo;
      #pragma unroll
      for (int i = 0; i < 8; ++i) {
        float v = pW1[(size_t)(kb + i)*128 + colg];
        short a, b, c; split3(v, a, b, c);
        h[i] = a; m[i] = b; lo[i] = c;
      }
      *(bf16x8*)&wUp[((size_t)((0*4 + ks)*8 + nt))*512 + ln*8] = h;
      *(bf16x8*)&wUp[((size_t)((1*4 + ks)*8 + nt))*512 + ln*8] = m;
      *(bf16x8*)&wUp[((size_t)((2*4 + ks)*8 + nt))*512 + ln*8] = lo;
    }
  }
}

// Unified fused GEMM (16x16x32 frags): A-row production + split-3 MFMA. 32 rows/block.
// Stage A: 4 channels/thread, b64 LDS writes. MFMA: A-frags hoisted per ks.
__global__ __launch_bounds__(512, 6) void k_gemm(
    const float* __restrict__ nf, const float* __restrict__ embW, const float* __restrict__ embB,
    float* __restrict__ node, const float* __restrict__ summed,
    const float* __restrict__ bsum2, const float* __restrict__ bsq2,
    const float* __restrict__ g2, const float* __restrict__ b2,
    const short* __restrict__ Wp, const float* __restrict__ bias,
    float* __restrict__ outS, float* __restrict__ outT,
    int NT, int mode, int writeNode) {
  __shared__ __align__(16) short sb[32*392];
  __shared__ float nfL[32][20];
  __shared__ float ewL[19][128];
  int tid = threadIdx.x;
  int n0 = blockIdx.x*32;
  if (mode == 0) {
    for (int i = tid; i < 32*19; i += 512) {
      int r = i/19, k = i - r*19;
      int n = n0 + r;
      nfL[r][k] = (n < NN) ? nf[(size_t)n*19 + k] : 0.f;
    }
    for (int i = tid; i < 19*128; i += 512) ewL[i >> 7][i & 127] = embW[i];
  }
  __syncthreads();
  {
    int c4 = (tid & 31)*4, rg = tid >> 5;    // 16 row-groups x 2 rows
    float4 sc4 = {0,0,0,0}, sh4 = {0,0,0,0}, eb4 = {0,0,0,0};
    if (mode == 0) {
      eb4 = *(const float4*)&embB[c4];
    } else {
      const float inv_n = 1.f / (float)NN;
      float4 su = *(const float4*)&bsum2[c4];
      float4 sq = *(const float4*)&bsq2[c4];
      float4 gg = *(const float4*)&g2[c4];
      float4 bb = *(const float4*)&b2[c4];
      float mu, var;
      mu = su.x*inv_n; var = sq.x*inv_n - mu*mu; sc4.x = gg.x*rsqrtf(var + BN_EPS); sh4.x = bb.x - mu*sc4.x;
      mu = su.y*inv_n; var = sq.y*inv_n - mu*mu; sc4.y = gg.y*rsqrtf(var + BN_EPS); sh4.y = bb.y - mu*sc4.y;
      mu = su.z*inv_n; var = sq.z*inv_n - mu*mu; sc4.z = gg.z*rsqrtf(var + BN_EPS); sh4.z = bb.z - mu*sc4.z;
      mu = su.w*inv_n; var = sq.w*inv_n - mu*mu; sc4.w = gg.w*rsqrtf(var + BN_EPS); sh4.w = bb.w - mu*sc4.w;
    }
    #pragma unroll
    for (int rr = 0; rr < 2; ++rr) {
      int r = rg*2 + rr;
      int n = n0 + r;
      float4 v = {0,0,0,0};
      if (n < NN) {
        if (mode == 0) {
          v = eb4;
          #pragma unroll
          for (int k = 0; k < 19; ++k) {
            float a = nfL[r][k];
            float4 w = *(const float4*)&ewL[k][c4];
            v.x = fmaf(a, w.x, v.x); v.y = fmaf(a, w.y, v.y);
            v.z = fmaf(a, w.z, v.z); v.w = fmaf(a, w.w, v.w);
          }
        } else {
          float4 nd = *(const float4*)&node[(size_t)n*F + c4];
          float4 sm = *(const float4*)&summed[(size_t)n*F + c4];
          float x;
          x = nd.x + fmaf(sm.x, sc4.x, sh4.x); v.x = fmaxf(x, 0.f) + log1pf(expf(-fabsf(x)));
          x = nd.y + fmaf(sm.y, sc4.y, sh4.y); v.y = fmaxf(x, 0.f) + log1pf(expf(-fabsf(x)));
          x = nd.z + fmaf(sm.z, sc4.z, sh4.z); v.z = fmaxf(x, 0.f) + log1pf(expf(-fabsf(x)));
          x = nd.w + fmaf(sm.w, sc4.w, sh4.w); v.w = fmaxf(x, 0.f) + log1pf(expf(-fabsf(x)));
        }
        if (writeNode) *(float4*)&node[(size_t)n*F + c4] = v;
      }
      short4 s0v, s1v, s2v;
      split3(v.x, s0v.x, s1v.x, s2v.x);
      split3(v.y, s0v.y, s1v.y, s2v.y);
      split3(v.z, s0v.z, s1v.z, s2v.z);
      split3(v.w, s0v.w, s1v.w, s2v.w);
      *(short4*)&sb[r*392 + c4]       = s0v;
      *(short4*)&sb[r*392 + 128 + c4] = s1v;
      *(short4*)&sb[r*392 + 256 + c4] = s2v;
    }
  }
  __syncthreads();
  int wv = tid >> 6, ln = tid & 63, lr = ln & 15, lg2 = ln >> 4;
  int ntpw = NT >> 3;            // 2 (conv) or 1 (k_u)
  f32x4v z4 = {0.f,0.f,0.f,0.f};
  f32x4v acc0[2] = {z4,z4};
  f32x4v acc1[2] = {z4,z4};
  int nt0 = wv*ntpw, nt1 = wv*ntpw + 1;
  for (int ks = 0; ks < 4; ++ks) {
    bf16x8 a[2][3];
    #pragma unroll
    for (int mt = 0; mt < 2; ++mt)
      #pragma unroll
      for (int as = 0; as < 3; ++as)
        a[mt][as] = *(const bf16x8*)&sb[(mt*16 + lr)*392 + as*128 + ks*32 + lg2*8];
    #pragma unroll
    for (int bs = 0; bs < 3; ++bs) {
      bf16x8 B0 = *(const bf16x8*)&Wp[((size_t)((bs*4 + ks)*NT + nt0))*512 + ln*8];
      bf16x8 B1 = B0;
      if (ntpw == 2) B1 = *(const bf16x8*)&Wp[((size_t)((bs*4 + ks)*NT + nt1))*512 + ln*8];
      int na = 3 - bs;
      #pragma unroll
      for (int as = 0; as < 3; ++as) {
        if (as >= na) break;
        #pragma unroll
        for (int mt = 0; mt < 2; ++mt) {
          acc0[mt] = __builtin_amdgcn_mfma_f32_16x16x32_bf16(a[mt][as], B0, acc0[mt], 0, 0, 0);
          if (ntpw == 2)
            acc1[mt] = __builtin_amdgcn_mfma_f32_16x16x32_bf16(a[mt][as], B1, acc1[mt], 0, 0, 0);
        }
      }
    }
  }
  {
    int col = nt0*16 + lr;
    float bb = (col < 128) ? bias[col] : 0.f;
    #pragma unroll
    for (int mt = 0; mt < 2; ++mt) {
      #pragma unroll
      for (int rr = 0; rr < 4; ++rr) {
        int row = n0 + mt*16 + lg2*4 + rr;
        if (row < NN) {
          float x = acc0[mt][rr] + bb;
          if (col < 128) outS[(size_t)row*F + col] = x;
          else outT[(size_t)row*F + col - 128] = x;
        }
      }
    }
  }
  if (ntpw == 2) {
    int col = nt1*16 + lr;
    float bb = (col < 128) ? bias[col] : 0.f;
    #pragma unroll
    for (int mt = 0; mt < 2; ++mt) {
      #pragma unroll
      for (int rr = 0; rr < 4; ++rr) {
        int row = n0 + mt*16 + lg2*4 + rr;
        if (row < NN) {
          float x = acc1[mt][rr] + bb;
          if (col < 128) outS[(size_t)row*F + col] = x;
          else outT[(size_t)row*F + col - 128] = x;
        }
      }
    }
  }
}

// pass 1: bn1 stats over all 480000 rows. Scalar channel-per-thread gather.
__global__ __launch_bounds__(256, 8) void k_stats(
    const float* __restrict__ S, const float* __restrict__ T,
    const float* __restrict__ Wl, const float* __restrict__ edge,
    const int* __restrict__ idx,
    float* __restrict__ bsum, float* __restrict__ bsq) {
  __shared__ float eL[1280];
  __shared__ int gL[256];
  __shared__ float rA[256], rB[256];
  int tid = threadIdx.x;
  int n0 = blockIdx.x*16;
  for (int i = tid; i < 1280; i += 256) eL[i] = edge[(size_t)n0*80 + i];
  {
    int v = idx[n0*MM + tid];
    gL[tid] = v < 0 ? v + NN : v;
  }
  __syncthreads();
  int c = tid & 127, h = tid >> 7;
  float we[5];
  #pragma unroll
  for (int j = 0; j < 5; ++j) we[j] = Wl[(size_t)(256+j)*256 + c];
  float s1 = 0.f, s2 = 0.f;
  for (int nl = h*8; nl < h*8 + 8; ++nl) {
    float sv = S[(size_t)(n0+nl)*F + c];
    #pragma unroll
    for (int m = 0; m < MM; ++m) {
      int row = nl*MM + m;
      float g = sv + T[(size_t)gL[row]*F + c];
      const float* e = &eL[row*5];
      #pragma unroll
      for (int j = 0; j < 5; ++j) g = fmaf(e[j], we[j], g);
      s1 += g; s2 = fmaf(g, g, s2);
    }
  }
  rA[tid] = s1; rB[tid] = s2;
  __syncthreads();
  if (h == 0) {
    atomicAdd(&bsum[c], s1 + rA[128 + c]);
    atomicAdd(&bsq[c],  s2 + rB[128 + c]);
  }
}

// pass 2: inline bn1 finalize; summed + bn2 stats. Scalar channel-per-thread gather.
__global__ __launch_bounds__(256, 6) void k_pass2(
    const float* __restrict__ S, const float* __restrict__ T,
    const float* __restrict__ Wl, const float* __restrict__ edge,
    const int* __restrict__ idx,
    const float* __restrict__ bsum1, const float* __restrict__ bsq1,
    const float* __restrict__ g1, const float* __restrict__ b1,
    float* __restrict__ summed, float* __restrict__ bsum2, float* __restrict__ bsq2) {
  __shared__ float eL[1280];
  __shared__ int gL[256];
  __shared__ float mk[256];
  __shared__ float rA[256], rB[256];
  int tid = threadIdx.x;
  int n0 = blockIdx.x*16;
  for (int i = tid; i < 1280; i += 256) eL[i] = edge[(size_t)n0*80 + i];
  {
    int v = idx[n0*MM + tid];
    mk[tid] = v >= 0 ? 1.f : 0.f;
    gL[tid] = v < 0 ? v + NN : v;
  }
  __syncthreads();
  int c = tid & 127, h = tid >> 7;
  float we[5];
  #pragma unroll
  for (int j = 0; j < 5; ++j) we[j] = Wl[(size_t)(256+j)*256 + c];
  float sc1v, sh1v;
  {
    const float inv_n = 1.f / (float)NMROWS;
    float mu = bsum1[c]*inv_n;
    float var = bsq1[c]*inv_n - mu*mu;
    sc1v = g1[c]*rsqrtf(var + BN_EPS);
    sh1v = b1[c] - mu*sc1v;
  }
  float st1 = 0.f, st2 = 0.f;
  for (int nl = h*8; nl < h*8 + 8; ++nl) {
    float sv = S[(size_t)(n0+nl)*F + c];
    float acc = 0.f;
    #pragma unroll
    for (int m = 0; m < MM; ++m) {
      int row = nl*MM + m;
      float g = sv + T[(size_t)gL[row]*F + c];
      const float* e = &eL[row*5];
      #pragma unroll
      for (int j = 0; j < 5; ++j) g = fmaf(e[j], we[j], g);
      float x = fmaf(g, sc1v, sh1v);
      float sig = 1.f/(1.f + expf(-x));
      acc = fmaf(mk[row]*sig, sig, acc);
    }
    summed[(size_t)(n0+nl)*F + c] = acc;
    st1 += acc; st2 = fmaf(acc, acc, st2);
  }
  rA[tid] = st1; rB[tid] = st2;
  __syncthreads();
  if (h == 0) {
    atomicAdd(&bsum2[c], st1 + rA[128 + c]);
    atomicAdd(&bsq2[c],  st2 + rB[128 + c]);
  }
}

// fold tiled-edge / repeated-distance / constant-tp columns of pi_W1
__global__ void k_pi_const(const float* __restrict__ W1, const float* __restrict__ b1,
                           const int* __restrict__ tp,
                           float* __restrict__ w1e, float* __restrict__ w1d, float* __restrict__ b1eff) {
  int c = threadIdx.x;
  float t = read_tp(tp);
  #pragma unroll
  for (int j = 0; j < 5; ++j) w1e[j*128 + c] = W1[(128+j)*128 + c] + W1[(133+j)*128 + c];
  float d = 0.f;
  #pragma unroll
  for (int r = 138; r < 143; ++r) d += W1[r*128 + c];
  w1d[c] = d;
  float tt = 0.f;
  #pragma unroll
  for (int r = 143; r < 148; ++r) tt += W1[r*128 + c];
  b1eff[c] = b1[c] + t*tt;
}

// pack W2 (128x256) and W3 (256x128) into 3-split bf16 16x16x32 B-fragment layout.
__global__ void k_packw(const float* __restrict__ W2, const float* __restrict__ W3,
                        short* __restrict__ w2p, short* __restrict__ w3p) {
  int tid = threadIdx.x;
  if (blockIdx.x == 0) {
    for (int it = 0; it < 8; ++it) {
      int slot = it*512 + tid;
      int ln = slot & 63, fr = slot >> 6;
      int nt = fr & 15, ks = fr >> 4;
      int col = nt*16 + (ln & 15);
      int kb = ks*32 + (ln >> 4)*8;
      bf16x8 h, m, l;
      #pragma unroll
      for (int i = 0; i < 8; ++i) {
        short a, b, c;
        split3(W2[(size_t)(kb + i)*256 + col], a, b, c);
        h[i] = a; m[i] = b; l[i] = c;
      }
      *(bf16x8*)&w2p[((size_t)((0*4 + ks)*16 + nt))*512 + ln*8] = h;
      *(bf16x8*)&w2p[((size_t)((1*4 + ks)*16 + nt))*512 + ln*8] = m;
      *(bf16x8*)&w2p[((size_t)((2*4 + ks)*16 + nt))*512 + ln*8] = l;
    }
  } else {
    for (int it = 0; it < 8; ++it) {
      int slot = it*512 + tid;
      int ln = slot & 63, fr = slot >> 6;
      int nt = fr & 7, ks = fr >> 3;
      int col = nt*16 + (ln & 15);
      int kb = ks*32 + (ln >> 4)*8;
      bf16x8 h, m, l;
      #pragma unroll
      for (int i = 0; i < 8; ++i) {
        short a, b, c;
        split3(W3[(size_t)(kb + i)*128 + col], a, b, c);
        h[i] = a; m[i] = b; l[i] = c;
      }
      *(bf16x8*)&w3p[((size_t)((0*8 + ks)*8 + nt))*512 + ln*8] = h;
      *(bf16x8*)&w3p[((size_t)((1*8 + ks)*8 + nt))*512 + ln*8] = m;
      *(bf16x8*)&w3p[((size_t)((2*8 + ks)*8 + nt))*512 + ln*8] = l;
    }
  }
}

// fused pi MLP via split-bf16 16x16x32 MFMA. 32 rows/block, 512 threads (8 waves), ~52KB LDS.
// Stage A: 4 channels/thread + b64 writes. Stages B/C: A-frags hoisted per ks.
__global__ __launch_bounds__(512, 6) void k_pi_mfma(
    const float* __restrict__ U, const float* __restrict__ b2,
    const float* __restrict__ b3, const float* __restrict__ W4, const float* __restrict__ b4,
    const short* __restrict__ w2p, const short* __restrict__ w3p,
    const float* __restrict__ edge, const int* __restrict__ idx, const float* __restrict__ dist,
    const int* __restrict__ tp,
    const float* __restrict__ w1e, const float* __restrict__ w1d,
    float* __restrict__ lgt) {
  __shared__ __align__(16) short buf[32*776];
  __shared__ float eeL[32][5];
  __shared__ float ddL[32];
  __shared__ int gxL[32], ivL[32];
  __shared__ float part[8][32];
  int tid = threadIdx.x;
  int rb = blockIdx.x*32;
  for (int i = tid; i < 160; i += 512) eeL[i/5][i%5] = edge[(size_t)rb*5 + i];
  if (tid < 32) {
    int v = idx[rb + tid];
    ivL[tid] = v;
    gxL[tid] = v < 0 ? v + NN : v;
    ddL[tid] = dist[rb + tid];
  }
  __syncthreads();

  // ---- stage A: h1 = relu(U[gather] + e@W1e + d*w1d), split3 -> LDS (4ch/thread, b64) ----
  {
    int c4 = (tid & 31)*4, rg = tid >> 5;   // 16 row-groups x 2 rows
    float4 wd4 = *(const float4*)&w1d[c4];
    float4 wE4[5];
    #pragma unroll
    for (int j = 0; j < 5; ++j) wE4[j] = *(const float4*)&w1e[j*128 + c4];
    #pragma unroll
    for (int rr = 0; rr < 2; ++rr) {
      int r = rg*2 + rr;
      float4 v = *(const float4*)&U[(size_t)gxL[r]*F + c4];
      float dd = ddL[r];
      v.x = fmaf(dd, wd4.x, v.x); v.y = fmaf(dd, wd4.y, v.y);
      v.z = fmaf(dd, wd4.z, v.z); v.w = fmaf(dd, wd4.w, v.w);
      #pragma unroll
      for (int j = 0; j < 5; ++j) {
        float ej = eeL[r][j];
        v.x = fmaf(ej, wE4[j].x, v.x); v.y = fmaf(ej, wE4[j].y, v.y);
        v.z = fmaf(ej, wE4[j].z, v.z); v.w = fmaf(ej, wE4[j].w, v.w);
      }
      v.x = fmaxf(v.x, 0.f); v.y = fmaxf(v.y, 0.f);
      v.z = fmaxf(v.z, 0.f); v.w = fmaxf(v.w, 0.f);
      short4 s0v, s1v, s2v;
      split3(v.x, s0v.x, s1v.x, s2v.x);
      split3(v.y, s0v.y, s1v.y, s2v.y);
      split3(v.z, s0v.z, s1v.z, s2v.z);
      split3(v.w, s0v.w, s1v.w, s2v.w);
      *(short4*)&buf[r*392 + c4]       = s0v;
      *(short4*)&buf[r*392 + 128 + c4] = s1v;
      *(short4*)&buf[r*392 + 256 + c4] = s2v;
    }
  }
  __syncthreads();

  int wv = tid >> 6, ln = tid & 63;
  int lr = ln & 15, lg2 = ln >> 4;
  f32x4v zz = {0.f, 0.f, 0.f, 0.f};

  // ---- stage B: h2 = relu(h1 @ W2 + b2); A-frags hoisted ----
  f32x4v accB[2][2];
  accB[0][0] = zz; accB[0][1] = zz; accB[1][0] = zz; accB[1][1] = zz;
  {
    int nt0 = wv*2, nt1 = wv*2 + 1;
    for (int ks = 0; ks < 4; ++ks) {
      bf16x8 a[2][3];
      #pragma unroll
      for (int mt = 0; mt < 2; ++mt)
        #pragma unroll
        for (int as = 0; as < 3; ++as)
          a[mt][as] = *(const bf16x8*)&buf[(mt*16 + lr)*392 + as*128 + ks*32 + lg2*8];
      #pragma unroll
      for (int bs = 0; bs < 3; ++bs) {
        bf16x8 B0 = *(const bf16x8*)&w2p[((size_t)((bs*4 + ks)*16 + nt0))*512 + ln*8];
        bf16x8 B1 = *(const bf16x8*)&w2p[((size_t)((bs*4 + ks)*16 + nt1))*512 + ln*8];
        int na = 3 - bs;
        #pragma unroll
        for (int as = 0; as < 3; ++as) {
          if (as >= na) break;
          #pragma unroll
          for (int mt = 0; mt < 2; ++mt) {
            accB[mt][0] = __builtin_amdgcn_mfma_f32_16x16x32_bf16(a[mt][as], B0, accB[mt][0], 0, 0, 0);
            accB[mt][1] = __builtin_amdgcn_mfma_f32_16x16x32_bf16(a[mt][as], B1, accB[mt][1], 0, 0, 0);
          }
        }
      }
    }
  }
  __syncthreads();
  {
    #pragma unroll
    for (int ntl = 0; ntl < 2; ++ntl) {
      int col = (wv*2 + ntl)*16 + lr;
      float bb = b2[col];
      #pragma unroll
      for (int mt = 0; mt < 2; ++mt) {
        #pragma unroll
        for (int r = 0; r < 4; ++r) {
          int row = mt*16 + lg2*4 + r;
          float x = fmaxf(accB[mt][ntl][r] + bb, 0.f);
          short s0, s1, s2; split3(x, s0, s1, s2);
          buf[row*776 + col] = s0; buf[row*776 + 256 + col] = s1; buf[row*776 + 512 + col] = s2;
        }
      }
    }
  }
  __syncthreads();

  // ---- stage C: h3 = relu(h2 @ W3 + b3); A-frags hoisted ----
  f32x4v accC[2];
  accC[0] = zz; accC[1] = zz;
  {
    for (int ks = 0; ks < 8; ++ks) {
      bf16x8 a[2][3];
      #pragma unroll
      for (int mt = 0; mt < 2; ++mt)
        #pragma unroll
        for (int as = 0; as < 3; ++as)
          a[mt][as] = *(const bf16x8*)&buf[(mt*16 + lr)*776 + as*256 + ks*32 + lg2*8];
      #pragma unroll
      for (int bs = 0; bs < 3; ++bs) {
        bf16x8 B = *(const bf16x8*)&w3p[((size_t)((bs*8 + ks)*8 + wv))*512 + ln*8];
        int na = 3 - bs;
        #pragma unroll
        for (int as = 0; as < 3; ++as) {
          if (as >= na) break;
          #pragma unroll
          for (int mt = 0; mt < 2; ++mt) {
            accC[mt] = __builtin_amdgcn_mfma_f32_16x16x32_bf16(a[mt][as], B, accC[mt], 0, 0, 0);
          }
        }
      }
    }
  }

  // ---- stage D: logit = relu(h3)@W4 (+b4) ----
  {
    float w4c = W4[wv*16 + lr];
    float b3c = b3[wv*16 + lr];
    #pragma unroll
    for (int mt = 0; mt < 2; ++mt) {
      float p0 = fmaxf(accC[mt][0] + b3c, 0.f) * w4c;
      float p1 = fmaxf(accC[mt][1] + b3c, 0.f) * w4c;
      float p2 = fmaxf(accC[mt][2] + b3c, 0.f) * w4c;
      float p3 = fmaxf(accC[mt][3] + b3c, 0.f) * w4c;
      #pragma unroll
      for (int off = 1; off < 16; off <<= 1) {
        p0 += __shfl_xor(p0, off, 16);
        p1 += __shfl_xor(p1, off, 16);
        p2 += __shfl_xor(p2, off, 16);
        p3 += __shfl_xor(p3, off, 16);
      }
      if (lr == 0) {
        int row = mt*16 + lg2*4;
        part[wv][row]   = p0;
        part[wv][row+1] = p1;
        part[wv][row+2] = p2;
        part[wv][row+3] = p3;
      }
    }
  }
  __syncthreads();
  if (tid < 32) {
    float s = 0.f;
    #pragma unroll
    for (int w = 0; w < 8; ++w) s += part[w][tid];
    float tpf = read_tp(tp);
    float lgv = s + b4[0];
    float am = (ivL[tid] >= 0 && eeL[tid][4] <= tpf) ? 0.f : 1.f;
    lgt[rb + tid] = lgv - 1e8f*am;
  }
}

// per-block max + sum(exp(x - bmax))
__global__ void k_pass1(const float* __restrict__ lg, float* __restrict__ red) {
  __shared__ float r[256];
  int t = threadIdx.x;
  float m = -3.4e38f;
  for (int i = blockIdx.x*256 + t; i < NMROWS; i += 512*256) m = fmaxf(m, lg[i]);
  r[t] = m; __syncthreads();
  for (int s = 128; s > 0; s >>= 1) {
    if (t < s) r[t] = fmaxf(r[t], r[t + s]);
    __syncthreads();
  }
  float bm = r[0];
  __syncthreads();
  float sum = 0.f;
  for (int i = blockIdx.x*256 + t; i < NMROWS; i += 512*256) sum += expf(lg[i] - bm);
  r[t] = sum; __syncthreads();
  for (int s = 128; s > 0; s >>= 1) {
    if (t < s) r[t] += r[t + s];
    __syncthreads();
  }
  if (t == 0) { red[blockIdx.x] = bm; red[512 + blockIdx.x] = r[0]; }
}

// final: redundant reduce per block, then write softmax
__global__ void k_out2(const float* __restrict__ lg, const float* __restrict__ red,
                       float* __restrict__ out) {
  __shared__ float r[256], z[256];
  int t = threadIdx.x;
  float m = fmaxf(red[t], red[t + 256]);
  r[t] = m; __syncthreads();
  for (int s = 128; s > 0; s >>= 1) {
    if (t < s) r[t] = fmaxf(r[t], r[t + s]);
    __syncthreads();
  }
  float gmax = r[0];
  __syncthreads();
  float zz = red[512 + t]*expf(red[t] - gmax) + red[768 + t]*expf(red[256 + t] - gmax);
  z[t] = zz; __syncthreads();
  for (int s = 128; s > 0; s >>= 1) {
    if (t < s) z[t] += z[t + s];
    __syncthreads();
  }
  float invZ = 1.f / z[0];
  int i = blockIdx.x*256 + t;
  if (i < NMROWS) out[i] = expf(lg[i] - gmax)*invZ;
}

extern "C" void kernel_launch(void* const* d_in, const int* in_sizes, int n_in,
                              void* d_out, int out_size, void* d_ws, size_t ws_size,
                              hipStream_t stream) {
  (void)in_sizes; (void)n_in; (void)out_size;
  const float* node_fea = (const float*)d_in[0];
  const float* edge_fea = (const float*)d_in[1];
  const int*   eidx     = (const int*)d_in[2];
  const float* dist     = (const float*)d_in[3];
  const int*   tp       = (const int*)d_in[4];
  const float* emb_W    = (const float*)d_in[5];
  const float* emb_b    = (const float*)d_in[6];
  const float* cW       = (const float*)d_in[7];
  const float* cb       = (const float*)d_in[8];
  const float* bn1g     = (const float*)d_in[9];
  const float* bn1b     = (const float*)d_in[10];
  const float* bn2g     = (const float*)d_in[11];
  const float* bn2b     = (const float*)d_in[12];
  const float* pW1      = (const float*)d_in[13];
  const float* pb1      = (const float*)d_in[14];
  const float* pW2      = (const float*)d_in[15];
  const float* pb2      = (const float*)d_in[16];
  const float* pW3      = (const float*)d_in[17];
  const float* pb3      = (const float*)d_in[18];
  const float* pW4      = (const float*)d_in[19];
  const float* pb4      = (const float*)d_in[20];
  float* out = (float*)d_out;
  float* ws  = (float*)d_ws;

  if (ws_size < (size_t)(WS_STATS + ST_END)*sizeof(float)) return;

  float* stats = ws + WS_STATS;
  float* node   = ws + WS_NODE;
  float* Sbuf   = ws + WS_S;
  float* Tbuf   = ws + WS_T;
  float* sumbuf = ws + WS_SUM;
  hipMemsetAsync(stats, 0, 1536*sizeof(float), stream);

  // packs living in the (not-yet-used) logits region
  short* convPack = (short*)(ws + WS_LOGIT);            // 294912 shorts
  short* wUp      = (short*)(ws + WS_LOGIT + 300000u);  // 49152 shorts
  k_pack_conv<<<4, 512, 0, stream>>>(cW, pW1, convPack, wUp);
  k_pi_const<<<1, 128, 0, stream>>>(pW1, pb1, tp, stats + ST_W1E, stats + ST_W1D, stats + ST_B1EFF);

  for (int l = 0; l < 3; ++l) {
    const float* Wl = cW + (size_t)l*261*256;
    if (l == 0) {
      k_gemm<<<938, 512, 0, stream>>>(node_fea, emb_W, emb_b, node,
                                      nullptr, nullptr, nullptr, nullptr, nullptr,
                                      convPack, cb, Sbuf, Tbuf, 16, 0, 1);
    } else {
      k_gemm<<<938, 512, 0, stream>>>(nullptr, nullptr, nullptr, node,
                                      sumbuf, stats + ST_BN2SUM + (l-1)*128, stats + ST_BN2SQ + (l-1)*128,
                                      bn2g + (l-1)*128, bn2b + (l-1)*128,
                                      convPack + (size_t)l*98304, cb + l*256, Sbuf, Tbuf, 16, 1, 1);
    }
    k_stats<<<1875, 256, 0, stream>>>(Sbuf, Tbuf, Wl, edge_fea, eidx,
                                      stats + ST_BN1SUM + l*128, stats + ST_BN1SQ + l*128);
    k_pass2<<<1875, 256, 0, stream>>>(Sbuf, Tbuf, Wl, edge_fea, eidx,
                                      stats + ST_BN1SUM + l*128, stats + ST_BN1SQ + l*128,
                                      bn1g + l*256, bn1b + l*256,
                                      sumbuf, stats + ST_BN2SUM + l*128, stats + ST_BN2SQ + l*128);
  }

  // pi packs into the (now dead) T region
  short* w2p = (short*)(ws + WS_T);             // 98304 shorts
  short* w3p = (short*)(ws + WS_T + 49152u);    // 98304 shorts
  k_packw<<<2, 512, 0, stream>>>(pW2, pW3, w2p, w3p);

  // U = softplus(node + bn2_l2(summed)) @ pi_W1[:128] + b1eff   (fused update, no node write)
  k_gemm<<<938, 512, 0, stream>>>(nullptr, nullptr, nullptr, node,
                                  sumbuf, stats + ST_BN2SUM + 2*128, stats + ST_BN2SQ + 2*128,
                                  bn2g + 2*128, bn2b + 2*128,
                                  wUp, stats + ST_B1EFF, Sbuf, Sbuf, 8, 1, 0);

  k_pi_mfma<<<15000, 512, 0, stream>>>(Sbuf, pb2, pb3, pW4, pb4, w2p, w3p,
                                       edge_fea, eidx, dist, tp,
                                       stats + ST_W1E, stats + ST_W1D, ws + WS_LOGIT);

  k_pass1<<<512, 256, 0, stream>>>(ws + WS_LOGIT, ws + WS_RED);
  k_out2<<<1875, 256, 0, stream>>>(ws + WS_LOGIT, ws + WS_RED, out);
}